// Round 9
// baseline (563.717 us; speedup 1.0000x reference)
//
#include <hip/hip_runtime.h>
#include <hip/hip_bf16.h>

// MultiHeadSelfAttention  B=2, S=4096, D=512, H=8, dk=64
// R9: attn key-axis split across blocks (2 chunks x 2048 keys): grid
//     (32,8,4)=1024 blocks -> 4 blocks/CU, 16 waves/CU (R8 was latency-bound
//     at 8 waves/CU: no pipe >36%). Chunks write f32 O/l partials; combine
//     kernel sums+normalizes (no-max softmax is associative over keys).
//     cast_x + wtrans fused into one prep dispatch.
// Wave split 2x2 (q 2x64, keys 2x32); S^T=K*Q^T in-register P packing;
// kappa key permutation baked into V^T global layout (unchanged from R8).

#define DMODEL 512
#define SEQ    4096
#define NTOK   8192
#define LDQK   1024

using f32x4 = __attribute__((ext_vector_type(4))) float;
using s16x8 = __attribute__((ext_vector_type(8))) short;
using u16x8 = __attribute__((ext_vector_type(8))) unsigned short;

static __device__ __forceinline__ unsigned short f2bf(float f) {
  union { float f; unsigned u; } v; v.f = f;
  unsigned r = v.u + 0x7fff + ((v.u >> 16) & 1);   // RNE
  return (unsigned short)(r >> 16);
}

static __device__ __forceinline__ unsigned pack_bf2(float lo, float hi) {
  __hip_bfloat162 t = __float22bfloat162_rn(make_float2(lo, hi));
  union { __hip_bfloat162 b; unsigned u; } c; c.b = t; return c.u;
}

// async global->LDS, 16B per lane; lds base wave-uniform, lane i -> base+16i.
static __device__ __forceinline__ void gll16(const void* g, void* l) {
  __builtin_amdgcn_global_load_lds(
      (const __attribute__((address_space(1))) unsigned int*)g,
      (__attribute__((address_space(3))) unsigned int*)l, 16, 0, 0);
}

// Fused prep: blocks 0..1023 cast x -> bf16; blocks 1024..1279 transpose one
// 64x64 tile of one W into Wall = [Wq'|Wk|Wv|Wo] (N-major), Wq scaled by c2.
__global__ void prep_kernel(const float* __restrict__ x,
                            const float* __restrict__ Wq,
                            const float* __restrict__ Wk,
                            const float* __restrict__ Wv,
                            const float* __restrict__ Wo,
                            unsigned short* __restrict__ xb,
                            unsigned short* __restrict__ Wall, float c2) {
  __shared__ float T[64][65];
  const int bx = blockIdx.x;
  if (bx < 1024) {
    for (int i = bx * 256 + threadIdx.x; i < NTOK * DMODEL / 4; i += 262144) {
      float4 v = ((const float4*)x)[i];
      ushort4 o;
      o.x = f2bf(v.x); o.y = f2bf(v.y); o.z = f2bf(v.z); o.w = f2bf(v.w);
      ((ushort4*)xb)[i] = o;
    }
    return;
  }
  const int t = bx - 1024;
  const int y = t >> 6, sub = t & 63;
  const float* W = (y == 0) ? Wq : (y == 1) ? Wk : (y == 2) ? Wv : Wo;
  const float scale = (y == 0) ? c2 : 1.0f;
  const int tk = (sub & 7) * 64;
  const int tn = (sub >> 3) * 64;
  const int r  = threadIdx.x >> 2;
  const int cq = threadIdx.x & 3;
#pragma unroll
  for (int i = 0; i < 4; ++i) {
    int c = (cq + 4 * i) * 4;
    float4 v = *(const float4*)&W[(size_t)(tk + r) * 512 + tn + c];
    T[r][c + 0] = v.x * scale; T[r][c + 1] = v.y * scale;
    T[r][c + 2] = v.z * scale; T[r][c + 3] = v.w * scale;
  }
  __syncthreads();
  const int n  = threadIdx.x >> 2;
  const int k0 = (threadIdx.x & 3) * 16;
#pragma unroll
  for (int j4 = 0; j4 < 4; ++j4) {
    ushort4 o;
    o.x = f2bf(T[k0 + j4 * 4 + 0][n]);
    o.y = f2bf(T[k0 + j4 * 4 + 1][n]);
    o.z = f2bf(T[k0 + j4 * 4 + 2][n]);
    o.w = f2bf(T[k0 + j4 * 4 + 3][n]);
    *(ushort4*)&Wall[(size_t)y * 262144 + (size_t)(tn + n) * 512 + tk + k0 + j4 * 4] = o;
  }
}

// Fused QK + V^T GEMM. grid (64, 12). global_load_lds staging (m97 2-barrier).
//  by 0..7 : QK block  — C[8192 x 1024] = xb @ [Wq'|Wk]^T, bf16 row-major.
//  by 8..11: V^T block — C[512 x 8192] = Wv_t @ xb^T, stored batched
//            [b][m=h*64+dk][s] with kappa-permuted s within 64-groups.
__global__ __launch_bounds__(256, 3) void gemm_qkv(
    const unsigned short* __restrict__ xb,
    const unsigned short* __restrict__ Wall,
    unsigned short* __restrict__ QKb,
    unsigned short* __restrict__ Vtb)
{
  __shared__ unsigned short As[128 * 32];
  __shared__ unsigned short Bs[128 * 32];
  const int by = blockIdx.y;
  const bool vmode = (by >= 8);
  const unsigned short* A  = vmode ? (Wall + 2 * 262144) : xb;
  const unsigned short* Bt = vmode ? xb : Wall;
  const size_t bm = vmode ? (size_t)(by - 8) * 128 : (size_t)blockIdx.x * 128;
  const size_t bn = vmode ? (size_t)blockIdx.x * 128 : (size_t)by * 128;
  const int tid  = threadIdx.x;
  const int wave = tid >> 6, lane = tid & 63;
  const int q4 = lane >> 4, ln = lane & 15;
  const int wm = (wave >> 1) * 64, wn = (wave & 1) * 64;
  f32x4 acc[4][4] = {};
  const int srow = wave * 16 + (lane >> 2);
  const int scol = (lane & 3) * 8;

  const unsigned short* Ag  = A  + (bm + srow)      * 512 + scol;
  const unsigned short* Ag2 = A  + (bm + 64 + srow) * 512 + scol;
  const unsigned short* Bg  = Bt + (bn + srow)      * 512 + scol;
  const unsigned short* Bg2 = Bt + (bn + 64 + srow) * 512 + scol;
  unsigned short* Ad  = As + wave * 512;
  unsigned short* Ad2 = As + 2048 + wave * 512;
  unsigned short* Bd  = Bs + wave * 512;
  unsigned short* Bd2 = Bs + 2048 + wave * 512;

  for (int kt = 0; kt < 512; kt += 32) {
    __syncthreads();
    gll16(Ag + kt,  Ad);
    gll16(Ag2 + kt, Ad2);
    gll16(Bg + kt,  Bd);
    gll16(Bg2 + kt, Bd2);
    __syncthreads();
    s16x8 af[4], bfr[4];
#pragma unroll
    for (int i = 0; i < 4; i++)
      af[i] = *(const s16x8*)(As + (wm + i * 16 + ln) * 32 + q4 * 8);
#pragma unroll
    for (int i = 0; i < 4; i++)
      bfr[i] = *(const s16x8*)(Bs + (wn + i * 16 + ln) * 32 + q4 * 8);
#pragma unroll
    for (int mi = 0; mi < 4; mi++)
#pragma unroll
      for (int ni = 0; ni < 4; ni++)
        acc[mi][ni] = __builtin_amdgcn_mfma_f32_16x16x32_bf16(
            af[mi], bfr[ni], acc[mi][ni], 0, 0, 0);
  }
#pragma unroll
  for (int mi = 0; mi < 4; mi++)
#pragma unroll
    for (int r = 0; r < 4; ++r) {
      size_t row = bm + wm + mi * 16 + q4 * 4 + r;
#pragma unroll
      for (int ni = 0; ni < 4; ni++) {
        size_t col = bn + wn + ni * 16 + ln;
        unsigned short hv = f2bf(acc[mi][ni][r]);
        if (!vmode) {
          QKb[row * 1024 + col] = hv;
        } else {
          int b = (int)(col >> 12), s = (int)(col & 4095);
          // kappa(s%64): slot holding key s for PV A-frag alignment
          int sp = (s & ~63) | (s & 32) | (((s >> 2) & 3) << 3) |
                   (((s >> 4) & 1) << 2) | (s & 3);
          Vtb[(size_t)b * 2097152 + row * 4096 + sp] = hv;
        }
      }
    }
}

// Flash-lite attention, key-split. grid (32 qt, 8 h, 4 z=b*2+chunk) = 1024.
// Block: 128 q-rows x 2048 keys (32 tiles). Waves 2x2: wq -> 64 q-rows,
// wk -> 32-key half of each tile. S^T = K*Q^T; P packed in-register into PV
// A-frags via kappa slots. O/l f32 partials per chunk; 1 barrier per tile.
__global__ __launch_bounds__(256, 4) void attn_kernel(
    const unsigned short* __restrict__ QK,   // NTOK x 1024 [Q'|K]
    const unsigned short* __restrict__ Vt,   // [b*8+h][64 dk][4096 s-kappa]
    float* __restrict__ Opart,               // [ck][8192][512] f32
    float* __restrict__ Lpart)               // [ck][b*8+h][4096] f32
{
  const int qt = blockIdx.x, h = blockIdx.y, z = blockIdx.z;
  const int b = z >> 1, ck = z & 1;
  const int tid = threadIdx.x, wave = tid >> 6, lane = tid & 63;
  const int q4 = lane >> 4, ln = lane & 15;
  const int wq = wave >> 1, wk = wave & 1;
  __shared__ __align__(16) unsigned char SM[36864];
  unsigned short* KsB = (unsigned short*)SM;            // [2][64*72]
  unsigned short* VsB = (unsigned short*)(SM + 18432);  // [2][64*72]
  const size_t rowbase = (size_t)b * SEQ;
  const size_t qrow0   = (size_t)qt * 128 + wq * 64;    // within-batch q row
  const unsigned short* Kp  = QK + rowbase * LDQK + 512 + h * 64;
  const unsigned short* VTp = Vt + ((size_t)(b * 8 + h) * 64) * SEQ;

  s16x8 qf[4][2];   // B-frags: q = qrow0 + nt*16 + ln, dk chunk c
#pragma unroll
  for (int nt = 0; nt < 4; ++nt) {
    const unsigned short* q = QK + (rowbase + qrow0 + nt * 16 + ln) * LDQK + h * 64;
    qf[nt][0] = *(const s16x8*)(q + q4 * 8);
    qf[nt][1] = *(const s16x8*)(q + 32 + q4 * 8);
  }
  f32x4 o[4][4] = {};   // [nt(q)][dt(dk)] partial over this chunk & wk keys
  float lp[4] = {};     // l partial for q = nt*16+ln

  const int srow = tid >> 2;            // 0..63
  const int scol = (tid & 3) * 16;      // 0,16,32,48

  const unsigned short* kgp = Kp  + ((size_t)(ck * 2048 + srow)) * LDQK + scol;
  const unsigned short* vgp = VTp + (size_t)srow * SEQ + ck * 2048 + scol;

  u16x8 kr  = *(const u16x8*)kgp;
  u16x8 kr2 = *(const u16x8*)(kgp + 8);
  u16x8 vr  = *(const u16x8*)vgp;
  u16x8 vr2 = *(const u16x8*)(vgp + 8);
  *(u16x8*)(KsB + srow * 72 + scol)     = kr;
  *(u16x8*)(KsB + srow * 72 + scol + 8) = kr2;
  *(u16x8*)(VsB + srow * 72 + scol)     = vr;
  *(u16x8*)(VsB + srow * 72 + scol + 8) = vr2;
  kgp += (size_t)64 * LDQK;  vgp += 64;
  kr  = *(const u16x8*)kgp;
  kr2 = *(const u16x8*)(kgp + 8);
  vr  = *(const u16x8*)vgp;
  vr2 = *(const u16x8*)(vgp + 8);
  __syncthreads();

  for (int t = 0; t < 32; ++t) {
    const int cur = t & 1;
    const unsigned short* Kc = KsB + cur * 4608;
    const unsigned short* Vc = VsB + cur * 4608;

    // S^T: A = K[m=key: wk*32+mi*16+ln][k=dk], B = Q[n=q][k=dk]
    f32x4 s4[2][4] = {};
#pragma unroll
    for (int mi = 0; mi < 2; ++mi)
#pragma unroll
      for (int c = 0; c < 2; ++c) {
        s16x8 kf = *(const s16x8*)(Kc + (wk * 32 + mi * 16 + ln) * 72 + c * 32 + q4 * 8);
#pragma unroll
        for (int nt = 0; nt < 4; ++nt)
          s4[mi][nt] = __builtin_amdgcn_mfma_f32_16x16x32_bf16(kf, qf[nt][c], s4[mi][nt], 0, 0, 0);
      }
    // V B-frags: B[k=slot wk*32+q4*8+j][n=dk dt*16+ln]
    s16x8 vf[4];
#pragma unroll
    for (int dt = 0; dt < 4; ++dt)
      vf[dt] = *(const s16x8*)(Vc + (dt * 16 + ln) * 72 + wk * 32 + q4 * 8);

    // p = exp2(s^T): keys wk*32+mi*16+q4*4+r -> slot 8q4+4mi+r -> elem j=4mi+r
    s16x8 pf[4];
#pragma unroll
    for (int nt = 0; nt < 4; ++nt) {
      float e00 = __builtin_amdgcn_exp2f(s4[0][nt][0]);
      float e01 = __builtin_amdgcn_exp2f(s4[0][nt][1]);
      float e02 = __builtin_amdgcn_exp2f(s4[0][nt][2]);
      float e03 = __builtin_amdgcn_exp2f(s4[0][nt][3]);
      float e10 = __builtin_amdgcn_exp2f(s4[1][nt][0]);
      float e11 = __builtin_amdgcn_exp2f(s4[1][nt][1]);
      float e12 = __builtin_amdgcn_exp2f(s4[1][nt][2]);
      float e13 = __builtin_amdgcn_exp2f(s4[1][nt][3]);
      lp[nt] += ((e00 + e01) + (e02 + e03)) + ((e10 + e11) + (e12 + e13));
      union { s16x8 v; unsigned u[4]; } pu;
      pu.u[0] = pack_bf2(e00, e01);
      pu.u[1] = pack_bf2(e02, e03);
      pu.u[2] = pack_bf2(e10, e11);
      pu.u[3] = pack_bf2(e12, e13);
      pf[nt] = pu.v;
    }
    // O += P V over the wave's 32 keys
#pragma unroll
    for (int nt = 0; nt < 4; ++nt)
#pragma unroll
      for (int dt = 0; dt < 4; ++dt)
        o[nt][dt] = __builtin_amdgcn_mfma_f32_16x16x32_bf16(pf[nt], vf[dt], o[nt][dt], 0, 0, 0);

    if (t + 1 < 32) {
      unsigned short* Kn = KsB + (cur ^ 1) * 4608;
      unsigned short* Vn = VsB + (cur ^ 1) * 4608;
      *(u16x8*)(Kn + srow * 72 + scol)     = kr;
      *(u16x8*)(Kn + srow * 72 + scol + 8) = kr2;
      *(u16x8*)(Vn + srow * 72 + scol)     = vr;
      *(u16x8*)(Vn + srow * 72 + scol + 8) = vr2;
      if (t + 2 < 32) {
        kgp += (size_t)64 * LDQK;  vgp += 64;
        kr  = *(const u16x8*)kgp;
        kr2 = *(const u16x8*)(kgp + 8);
        vr  = *(const u16x8*)vgp;
        vr2 = *(const u16x8*)(vgp + 8);
      }
    }
    __syncthreads();   // single barrier per tile
  }

  // intra-wave l: sum q4 replicas
#pragma unroll
  for (int nt = 0; nt < 4; ++nt) {
    lp[nt] += __shfl_xor(lp[nt], 16, 64);
    lp[nt] += __shfl_xor(lp[nt], 32, 64);
  }
  // cross-wave (wk) reduction of O and l via LDS (K/V buffers reused)
  float* Red  = (float*)SM;            // 32KB: [wq*16+nt*4+dt][lane] f32x4
  float* RedL = (float*)(SM + 32768);  // 2KB : [wq*4+nt][lane]
  if (wk == 1) {
#pragma unroll
    for (int nt = 0; nt < 4; ++nt) {
#pragma unroll
      for (int dt = 0; dt < 4; ++dt)
        *(f32x4*)(Red + ((wq * 16 + nt * 4 + dt) * 64 + lane) * 4) = o[nt][dt];
      RedL[(wq * 4 + nt) * 64 + lane] = lp[nt];
    }
  }
  __syncthreads();
  if (wk == 0) {
    float* Opc = Opart + (size_t)ck * NTOK * DMODEL;
#pragma unroll
    for (int nt = 0; nt < 4; ++nt) {
#pragma unroll
      for (int dt = 0; dt < 4; ++dt)
        o[nt][dt] += *(const f32x4*)(Red + ((wq * 16 + nt * 4 + dt) * 64 + lane) * 4);
      lp[nt] += RedL[(wq * 4 + nt) * 64 + lane];
      if (q4 == 0)
        Lpart[(size_t)ck * 65536 + (size_t)(b * 8 + h) * 4096 + qrow0 + nt * 16 + ln] = lp[nt];
    }
#pragma unroll
    for (int nt = 0; nt < 4; ++nt)
#pragma unroll
      for (int r = 0; r < 4; ++r) {
        size_t row = rowbase + qrow0 + nt * 16 + q4 * 4 + r;
#pragma unroll
        for (int dt = 0; dt < 4; ++dt)
          Opc[row * DMODEL + h * 64 + dt * 16 + ln] = o[nt][dt][r];
      }
  }
}

// combine: Oc[row][c] = (Op0+Op1)/(l0+l1), bf16. grid 4096 x 256.
__global__ void combine_kernel(const float* __restrict__ Opart,
                               const float* __restrict__ Lpart,
                               unsigned short* __restrict__ Oc) {
  int i = blockIdx.x * 256 + threadIdx.x;       // 0..1048575
  int row = i >> 7;                             // 0..8191
  int c4  = (i & 127) * 4;                      // 0..508
  int b = row >> 12, qrow = row & 4095, h = c4 >> 6;
  float l = Lpart[(size_t)(b * 8 + h) * 4096 + qrow] +
            Lpart[65536 + (size_t)(b * 8 + h) * 4096 + qrow];
  float inv = 1.0f / l;
  f32x4 a = *(const f32x4*)(Opart + (size_t)row * 512 + c4);
  f32x4 c = *(const f32x4*)(Opart + (size_t)NTOK * DMODEL + (size_t)row * 512 + c4);
  float r0 = (a[0] + c[0]) * inv, r1 = (a[1] + c[1]) * inv;
  float r2 = (a[2] + c[2]) * inv, r3 = (a[3] + c[3]) * inv;
  uint2 w;
  w.x = pack_bf2(r0, r1);
  w.y = pack_bf2(r2, r3);
  *(uint2*)&Oc[(size_t)row * 512 + c4] = w;
}

// out = Oc @ Wo^T : M=8192 N=512 K=512, tile 128x64 (512 blocks = 2/CU), f32.
__global__ __launch_bounds__(256, 3) void gemm_out(
    const unsigned short* __restrict__ A,
    const unsigned short* __restrict__ Bt,
    float* __restrict__ C)
{
  __shared__ unsigned short As[128 * 32];
  __shared__ unsigned short Bs[64 * 32];
  const int tid  = threadIdx.x;
  const int wave = tid >> 6, lane = tid & 63;
  const int q4 = lane >> 4, ln = lane & 15;
  const size_t bm = (size_t)blockIdx.x * 128;
  const size_t bn = (size_t)blockIdx.y * 64;
  const int wm = (wave >> 1) * 64, wn = (wave & 1) * 32;
  f32x4 acc[4][2] = {};
  const int srow = wave * 16 + (lane >> 2);
  const int scol = (lane & 3) * 8;

  const unsigned short* Ag  = A  + (bm + srow)      * 512 + scol;
  const unsigned short* Ag2 = A  + (bm + 64 + srow) * 512 + scol;
  const unsigned short* Bg  = Bt + (bn + srow)      * 512 + scol;
  unsigned short* Ad  = As + wave * 512;
  unsigned short* Ad2 = As + 2048 + wave * 512;
  unsigned short* Bd  = Bs + wave * 512;

  for (int kt = 0; kt < 512; kt += 32) {
    __syncthreads();
    gll16(Ag + kt,  Ad);
    gll16(Ag2 + kt, Ad2);
    gll16(Bg + kt,  Bd);
    __syncthreads();
    s16x8 af[4], bfr[2];
#pragma unroll
    for (int i = 0; i < 4; i++)
      af[i] = *(const s16x8*)(As + (wm + i * 16 + ln) * 32 + q4 * 8);
#pragma unroll
    for (int i = 0; i < 2; i++)
      bfr[i] = *(const s16x8*)(Bs + (wn + i * 16 + ln) * 32 + q4 * 8);
#pragma unroll
    for (int mi = 0; mi < 4; mi++)
#pragma unroll
      for (int ni = 0; ni < 2; ni++)
        acc[mi][ni] = __builtin_amdgcn_mfma_f32_16x16x32_bf16(
            af[mi], bfr[ni], acc[mi][ni], 0, 0, 0);
  }
#pragma unroll
  for (int mi = 0; mi < 4; mi++)
#pragma unroll
    for (int r = 0; r < 4; ++r) {
      size_t row = bm + wm + mi * 16 + q4 * 4 + r;
#pragma unroll
      for (int ni = 0; ni < 2; ni++)
        C[row * 512 + bn + wn + ni * 16 + ln] = acc[mi][ni][r];
    }
}

extern "C" void kernel_launch(void* const* d_in, const int* in_sizes, int n_in,
                              void* d_out, int out_size, void* d_ws, size_t ws_size,
                              hipStream_t stream) {
  const float* x  = (const float*)d_in[0];
  const float* Wq = (const float*)d_in[1];
  const float* Wk = (const float*)d_in[2];
  const float* Wv = (const float*)d_in[3];
  const float* Wo = (const float*)d_in[4];

  char* ws = (char*)d_ws;
  unsigned short* xb    = (unsigned short*)(ws);              //  8,388,608
  unsigned short* Wall  = (unsigned short*)(ws + 8388608);    //  2,097,152
  unsigned short* QKb   = (unsigned short*)(ws + 10485760);   // 16,777,216
  unsigned short* Vtb   = (unsigned short*)(ws + 27262976);   //  8,388,608
  unsigned short* Oc    = (unsigned short*)(ws + 35651584);   //  8,388,608
  float*          Opart = (float*)(ws + 44040192);            // 33,554,432
  float*          Lpart = (float*)(ws + 77594624);            //    524,288

  const float C2 = 0.125f * 1.44269504088896f;  // 1/sqrt(64) * log2(e)

  hipLaunchKernelGGL(prep_kernel, dim3(1280), dim3(256), 0, stream,
                     x, Wq, Wk, Wv, Wo, xb, Wall, C2);
  hipLaunchKernelGGL(gemm_qkv, dim3(64, 12), dim3(256), 0, stream,
                     xb, Wall, QKb, Vtb);
  hipLaunchKernelGGL(attn_kernel, dim3(32, 8, 4), dim3(256), 0, stream,
                     QKb, Vtb, Opart, Lpart);
  hipLaunchKernelGGL(combine_kernel, dim3(4096), dim3(256), 0, stream,
                     Opart, Lpart, Oc);
  hipLaunchKernelGGL(gemm_out, dim3(64, 8), dim3(256), 0, stream,
                     Oc, Wall + 3 * 262144, (float*)d_out);
}

// Round 10
// 192.796 us; speedup vs baseline: 2.9239x; 2.9239x over previous
//
#include <hip/hip_runtime.h>
#include <hip/hip_bf16.h>

// MultiHeadSelfAttention  B=2, S=4096, D=512, H=8, dk=64
// R10: R9 key-split retry WITHOUT the register squeeze. R9's launch_bounds
//     (256,4) forced VGPR 100->64 => scratch spills (FETCH/WRITE ~1GB each,
//     attn 450us). Same body at (256,2) compiles to ~100 VGPR (R8-proven);
//     runtime occupancy still 4 blocks/CU (VGPR 100<=128, LDS 36.9KB*4<=160).
// attn key-axis split across blocks (2 chunks x 2048 keys), grid (32,8,4);
// chunks write f32 O/l partials; combine kernel sums+normalizes.
// Wave split 2x2 (q 2x64, keys 2x32); S^T=K*Q^T in-register P packing;
// kappa key permutation baked into V^T global layout.

#define DMODEL 512
#define SEQ    4096
#define NTOK   8192
#define LDQK   1024

using f32x4 = __attribute__((ext_vector_type(4))) float;
using s16x8 = __attribute__((ext_vector_type(8))) short;
using u16x8 = __attribute__((ext_vector_type(8))) unsigned short;

static __device__ __forceinline__ unsigned short f2bf(float f) {
  union { float f; unsigned u; } v; v.f = f;
  unsigned r = v.u + 0x7fff + ((v.u >> 16) & 1);   // RNE
  return (unsigned short)(r >> 16);
}

static __device__ __forceinline__ unsigned pack_bf2(float lo, float hi) {
  __hip_bfloat162 t = __float22bfloat162_rn(make_float2(lo, hi));
  union { __hip_bfloat162 b; unsigned u; } c; c.b = t; return c.u;
}

// async global->LDS, 16B per lane; lds base wave-uniform, lane i -> base+16i.
static __device__ __forceinline__ void gll16(const void* g, void* l) {
  __builtin_amdgcn_global_load_lds(
      (const __attribute__((address_space(1))) unsigned int*)g,
      (__attribute__((address_space(3))) unsigned int*)l, 16, 0, 0);
}

// Fused prep: blocks 0..1023 cast x -> bf16; blocks 1024..1279 transpose one
// 64x64 tile of one W into Wall = [Wq'|Wk|Wv|Wo] (N-major), Wq scaled by c2.
__global__ void prep_kernel(const float* __restrict__ x,
                            const float* __restrict__ Wq,
                            const float* __restrict__ Wk,
                            const float* __restrict__ Wv,
                            const float* __restrict__ Wo,
                            unsigned short* __restrict__ xb,
                            unsigned short* __restrict__ Wall, float c2) {
  __shared__ float T[64][65];
  const int bx = blockIdx.x;
  if (bx < 1024) {
    for (int i = bx * 256 + threadIdx.x; i < NTOK * DMODEL / 4; i += 262144) {
      float4 v = ((const float4*)x)[i];
      ushort4 o;
      o.x = f2bf(v.x); o.y = f2bf(v.y); o.z = f2bf(v.z); o.w = f2bf(v.w);
      ((ushort4*)xb)[i] = o;
    }
    return;
  }
  const int t = bx - 1024;
  const int y = t >> 6, sub = t & 63;
  const float* W = (y == 0) ? Wq : (y == 1) ? Wk : (y == 2) ? Wv : Wo;
  const float scale = (y == 0) ? c2 : 1.0f;
  const int tk = (sub & 7) * 64;
  const int tn = (sub >> 3) * 64;
  const int r  = threadIdx.x >> 2;
  const int cq = threadIdx.x & 3;
#pragma unroll
  for (int i = 0; i < 4; ++i) {
    int c = (cq + 4 * i) * 4;
    float4 v = *(const float4*)&W[(size_t)(tk + r) * 512 + tn + c];
    T[r][c + 0] = v.x * scale; T[r][c + 1] = v.y * scale;
    T[r][c + 2] = v.z * scale; T[r][c + 3] = v.w * scale;
  }
  __syncthreads();
  const int n  = threadIdx.x >> 2;
  const int k0 = (threadIdx.x & 3) * 16;
#pragma unroll
  for (int j4 = 0; j4 < 4; ++j4) {
    ushort4 o;
    o.x = f2bf(T[k0 + j4 * 4 + 0][n]);
    o.y = f2bf(T[k0 + j4 * 4 + 1][n]);
    o.z = f2bf(T[k0 + j4 * 4 + 2][n]);
    o.w = f2bf(T[k0 + j4 * 4 + 3][n]);
    *(ushort4*)&Wall[(size_t)y * 262144 + (size_t)(tn + n) * 512 + tk + k0 + j4 * 4] = o;
  }
}

// Fused QK + V^T GEMM. grid (64, 12). global_load_lds staging (m97 2-barrier).
//  by 0..7 : QK block  — C[8192 x 1024] = xb @ [Wq'|Wk]^T, bf16 row-major.
//  by 8..11: V^T block — C[512 x 8192] = Wv_t @ xb^T, stored batched
//            [b][m=h*64+dk][s] with kappa-permuted s within 64-groups.
__global__ __launch_bounds__(256, 3) void gemm_qkv(
    const unsigned short* __restrict__ xb,
    const unsigned short* __restrict__ Wall,
    unsigned short* __restrict__ QKb,
    unsigned short* __restrict__ Vtb)
{
  __shared__ unsigned short As[128 * 32];
  __shared__ unsigned short Bs[128 * 32];
  const int by = blockIdx.y;
  const bool vmode = (by >= 8);
  const unsigned short* A  = vmode ? (Wall + 2 * 262144) : xb;
  const unsigned short* Bt = vmode ? xb : Wall;
  const size_t bm = vmode ? (size_t)(by - 8) * 128 : (size_t)blockIdx.x * 128;
  const size_t bn = vmode ? (size_t)blockIdx.x * 128 : (size_t)by * 128;
  const int tid  = threadIdx.x;
  const int wave = tid >> 6, lane = tid & 63;
  const int q4 = lane >> 4, ln = lane & 15;
  const int wm = (wave >> 1) * 64, wn = (wave & 1) * 64;
  f32x4 acc[4][4] = {};
  const int srow = wave * 16 + (lane >> 2);
  const int scol = (lane & 3) * 8;

  const unsigned short* Ag  = A  + (bm + srow)      * 512 + scol;
  const unsigned short* Ag2 = A  + (bm + 64 + srow) * 512 + scol;
  const unsigned short* Bg  = Bt + (bn + srow)      * 512 + scol;
  const unsigned short* Bg2 = Bt + (bn + 64 + srow) * 512 + scol;
  unsigned short* Ad  = As + wave * 512;
  unsigned short* Ad2 = As + 2048 + wave * 512;
  unsigned short* Bd  = Bs + wave * 512;
  unsigned short* Bd2 = Bs + 2048 + wave * 512;

  for (int kt = 0; kt < 512; kt += 32) {
    __syncthreads();
    gll16(Ag + kt,  Ad);
    gll16(Ag2 + kt, Ad2);
    gll16(Bg + kt,  Bd);
    gll16(Bg2 + kt, Bd2);
    __syncthreads();
    s16x8 af[4], bfr[4];
#pragma unroll
    for (int i = 0; i < 4; i++)
      af[i] = *(const s16x8*)(As + (wm + i * 16 + ln) * 32 + q4 * 8);
#pragma unroll
    for (int i = 0; i < 4; i++)
      bfr[i] = *(const s16x8*)(Bs + (wn + i * 16 + ln) * 32 + q4 * 8);
#pragma unroll
    for (int mi = 0; mi < 4; mi++)
#pragma unroll
      for (int ni = 0; ni < 4; ni++)
        acc[mi][ni] = __builtin_amdgcn_mfma_f32_16x16x32_bf16(
            af[mi], bfr[ni], acc[mi][ni], 0, 0, 0);
  }
#pragma unroll
  for (int mi = 0; mi < 4; mi++)
#pragma unroll
    for (int r = 0; r < 4; ++r) {
      size_t row = bm + wm + mi * 16 + q4 * 4 + r;
#pragma unroll
      for (int ni = 0; ni < 4; ni++) {
        size_t col = bn + wn + ni * 16 + ln;
        unsigned short hv = f2bf(acc[mi][ni][r]);
        if (!vmode) {
          QKb[row * 1024 + col] = hv;
        } else {
          int b = (int)(col >> 12), s = (int)(col & 4095);
          // kappa(s%64): slot holding key s for PV A-frag alignment
          int sp = (s & ~63) | (s & 32) | (((s >> 2) & 3) << 3) |
                   (((s >> 4) & 1) << 2) | (s & 3);
          Vtb[(size_t)b * 2097152 + row * 4096 + sp] = hv;
        }
      }
    }
}

// Flash-lite attention, key-split. grid (32 qt, 8 h, 4 z=b*2+chunk) = 1024.
// Block: 128 q-rows x 2048 keys (32 tiles). Waves 2x2: wq -> 64 q-rows,
// wk -> 32-key half of each tile. S^T = K*Q^T; P packed in-register into PV
// A-frags via kappa slots. O/l f32 partials per chunk; 1 barrier per tile.
// launch_bounds(256,2): DO NOT raise min-waves — (256,4) forced VGPR 64 and
// spilled ~2GB of scratch traffic (R9). Runtime still fits 4 blocks/CU.
__global__ __launch_bounds__(256, 2) void attn_kernel(
    const unsigned short* __restrict__ QK,   // NTOK x 1024 [Q'|K]
    const unsigned short* __restrict__ Vt,   // [b*8+h][64 dk][4096 s-kappa]
    float* __restrict__ Opart,               // [ck][8192][512] f32
    float* __restrict__ Lpart)               // [ck][b*8+h][4096] f32
{
  const int qt = blockIdx.x, h = blockIdx.y, z = blockIdx.z;
  const int b = z >> 1, ck = z & 1;
  const int tid = threadIdx.x, wave = tid >> 6, lane = tid & 63;
  const int q4 = lane >> 4, ln = lane & 15;
  const int wq = wave >> 1, wk = wave & 1;
  __shared__ __align__(16) unsigned char SM[36864];
  unsigned short* KsB = (unsigned short*)SM;            // [2][64*72]
  unsigned short* VsB = (unsigned short*)(SM + 18432);  // [2][64*72]
  const size_t rowbase = (size_t)b * SEQ;
  const size_t qrow0   = (size_t)qt * 128 + wq * 64;    // within-batch q row
  const unsigned short* Kp  = QK + rowbase * LDQK + 512 + h * 64;
  const unsigned short* VTp = Vt + ((size_t)(b * 8 + h) * 64) * SEQ;

  s16x8 qf[4][2];   // B-frags: q = qrow0 + nt*16 + ln, dk chunk c
#pragma unroll
  for (int nt = 0; nt < 4; ++nt) {
    const unsigned short* q = QK + (rowbase + qrow0 + nt * 16 + ln) * LDQK + h * 64;
    qf[nt][0] = *(const s16x8*)(q + q4 * 8);
    qf[nt][1] = *(const s16x8*)(q + 32 + q4 * 8);
  }
  f32x4 o[4][4] = {};   // [nt(q)][dt(dk)] partial over this chunk & wk keys
  float lp[4] = {};     // l partial for q = nt*16+ln

  const int srow = tid >> 2;            // 0..63
  const int scol = (tid & 3) * 16;      // 0,16,32,48

  const unsigned short* kgp = Kp  + ((size_t)(ck * 2048 + srow)) * LDQK + scol;
  const unsigned short* vgp = VTp + (size_t)srow * SEQ + ck * 2048 + scol;

  u16x8 kr  = *(const u16x8*)kgp;
  u16x8 kr2 = *(const u16x8*)(kgp + 8);
  u16x8 vr  = *(const u16x8*)vgp;
  u16x8 vr2 = *(const u16x8*)(vgp + 8);
  *(u16x8*)(KsB + srow * 72 + scol)     = kr;
  *(u16x8*)(KsB + srow * 72 + scol + 8) = kr2;
  *(u16x8*)(VsB + srow * 72 + scol)     = vr;
  *(u16x8*)(VsB + srow * 72 + scol + 8) = vr2;
  kgp += (size_t)64 * LDQK;  vgp += 64;
  kr  = *(const u16x8*)kgp;
  kr2 = *(const u16x8*)(kgp + 8);
  vr  = *(const u16x8*)vgp;
  vr2 = *(const u16x8*)(vgp + 8);
  __syncthreads();

  for (int t = 0; t < 32; ++t) {
    const int cur = t & 1;
    const unsigned short* Kc = KsB + cur * 4608;
    const unsigned short* Vc = VsB + cur * 4608;

    // S^T: A = K[m=key: wk*32+mi*16+ln][k=dk], B = Q[n=q][k=dk]
    f32x4 s4[2][4] = {};
#pragma unroll
    for (int mi = 0; mi < 2; ++mi)
#pragma unroll
      for (int c = 0; c < 2; ++c) {
        s16x8 kf = *(const s16x8*)(Kc + (wk * 32 + mi * 16 + ln) * 72 + c * 32 + q4 * 8);
#pragma unroll
        for (int nt = 0; nt < 4; ++nt)
          s4[mi][nt] = __builtin_amdgcn_mfma_f32_16x16x32_bf16(kf, qf[nt][c], s4[mi][nt], 0, 0, 0);
      }
    // V B-frags: B[k=slot wk*32+q4*8+j][n=dk dt*16+ln]
    s16x8 vf[4];
#pragma unroll
    for (int dt = 0; dt < 4; ++dt)
      vf[dt] = *(const s16x8*)(Vc + (dt * 16 + ln) * 72 + wk * 32 + q4 * 8);

    // p = exp2(s^T): keys wk*32+mi*16+q4*4+r -> slot 8q4+4mi+r -> elem j=4mi+r
    s16x8 pf[4];
#pragma unroll
    for (int nt = 0; nt < 4; ++nt) {
      float e00 = __builtin_amdgcn_exp2f(s4[0][nt][0]);
      float e01 = __builtin_amdgcn_exp2f(s4[0][nt][1]);
      float e02 = __builtin_amdgcn_exp2f(s4[0][nt][2]);
      float e03 = __builtin_amdgcn_exp2f(s4[0][nt][3]);
      float e10 = __builtin_amdgcn_exp2f(s4[1][nt][0]);
      float e11 = __builtin_amdgcn_exp2f(s4[1][nt][1]);
      float e12 = __builtin_amdgcn_exp2f(s4[1][nt][2]);
      float e13 = __builtin_amdgcn_exp2f(s4[1][nt][3]);
      lp[nt] += ((e00 + e01) + (e02 + e03)) + ((e10 + e11) + (e12 + e13));
      union { s16x8 v; unsigned u[4]; } pu;
      pu.u[0] = pack_bf2(e00, e01);
      pu.u[1] = pack_bf2(e02, e03);
      pu.u[2] = pack_bf2(e10, e11);
      pu.u[3] = pack_bf2(e12, e13);
      pf[nt] = pu.v;
    }
    // O += P V over the wave's 32 keys
#pragma unroll
    for (int nt = 0; nt < 4; ++nt)
#pragma unroll
      for (int dt = 0; dt < 4; ++dt)
        o[nt][dt] = __builtin_amdgcn_mfma_f32_16x16x32_bf16(pf[nt], vf[dt], o[nt][dt], 0, 0, 0);

    if (t + 1 < 32) {
      unsigned short* Kn = KsB + (cur ^ 1) * 4608;
      unsigned short* Vn = VsB + (cur ^ 1) * 4608;
      *(u16x8*)(Kn + srow * 72 + scol)     = kr;
      *(u16x8*)(Kn + srow * 72 + scol + 8) = kr2;
      *(u16x8*)(Vn + srow * 72 + scol)     = vr;
      *(u16x8*)(Vn + srow * 72 + scol + 8) = vr2;
      if (t + 2 < 32) {
        kgp += (size_t)64 * LDQK;  vgp += 64;
        kr  = *(const u16x8*)kgp;
        kr2 = *(const u16x8*)(kgp + 8);
        vr  = *(const u16x8*)vgp;
        vr2 = *(const u16x8*)(vgp + 8);
      }
    }
    __syncthreads();   // single barrier per tile
  }

  // intra-wave l: sum q4 replicas
#pragma unroll
  for (int nt = 0; nt < 4; ++nt) {
    lp[nt] += __shfl_xor(lp[nt], 16, 64);
    lp[nt] += __shfl_xor(lp[nt], 32, 64);
  }
  // cross-wave (wk) reduction of O and l via LDS (K/V buffers reused)
  float* Red  = (float*)SM;            // 32KB: [wq*16+nt*4+dt][lane] f32x4
  float* RedL = (float*)(SM + 32768);  // 2KB : [wq*4+nt][lane]
  if (wk == 1) {
#pragma unroll
    for (int nt = 0; nt < 4; ++nt) {
#pragma unroll
      for (int dt = 0; dt < 4; ++dt)
        *(f32x4*)(Red + ((wq * 16 + nt * 4 + dt) * 64 + lane) * 4) = o[nt][dt];
      RedL[(wq * 4 + nt) * 64 + lane] = lp[nt];
    }
  }
  __syncthreads();
  if (wk == 0) {
    float* Opc = Opart + (size_t)ck * NTOK * DMODEL;
#pragma unroll
    for (int nt = 0; nt < 4; ++nt) {
#pragma unroll
      for (int dt = 0; dt < 4; ++dt)
        o[nt][dt] += *(const f32x4*)(Red + ((wq * 16 + nt * 4 + dt) * 64 + lane) * 4);
      lp[nt] += RedL[(wq * 4 + nt) * 64 + lane];
      if (q4 == 0)
        Lpart[(size_t)ck * 65536 + (size_t)(b * 8 + h) * 4096 + qrow0 + nt * 16 + ln] = lp[nt];
    }
#pragma unroll
    for (int nt = 0; nt < 4; ++nt)
#pragma unroll
      for (int r = 0; r < 4; ++r) {
        size_t row = rowbase + qrow0 + nt * 16 + q4 * 4 + r;
#pragma unroll
        for (int dt = 0; dt < 4; ++dt)
          Opc[row * DMODEL + h * 64 + dt * 16 + ln] = o[nt][dt][r];
      }
  }
}

// combine: Oc[row][c] = (Op0+Op1)/(l0+l1), bf16. grid 4096 x 256.
__global__ void combine_kernel(const float* __restrict__ Opart,
                               const float* __restrict__ Lpart,
                               unsigned short* __restrict__ Oc) {
  int i = blockIdx.x * 256 + threadIdx.x;       // 0..1048575
  int row = i >> 7;                             // 0..8191
  int c4  = (i & 127) * 4;                      // 0..508
  int b = row >> 12, qrow = row & 4095, h = c4 >> 6;
  float l = Lpart[(size_t)(b * 8 + h) * 4096 + qrow] +
            Lpart[65536 + (size_t)(b * 8 + h) * 4096 + qrow];
  float inv = 1.0f / l;
  f32x4 a = *(const f32x4*)(Opart + (size_t)row * 512 + c4);
  f32x4 c = *(const f32x4*)(Opart + (size_t)NTOK * DMODEL + (size_t)row * 512 + c4);
  float r0 = (a[0] + c[0]) * inv, r1 = (a[1] + c[1]) * inv;
  float r2 = (a[2] + c[2]) * inv, r3 = (a[3] + c[3]) * inv;
  uint2 w;
  w.x = pack_bf2(r0, r1);
  w.y = pack_bf2(r2, r3);
  *(uint2*)&Oc[(size_t)row * 512 + c4] = w;
}

// out = Oc @ Wo^T : M=8192 N=512 K=512, tile 128x64 (512 blocks = 2/CU), f32.
__global__ __launch_bounds__(256, 3) void gemm_out(
    const unsigned short* __restrict__ A,
    const unsigned short* __restrict__ Bt,
    float* __restrict__ C)
{
  __shared__ unsigned short As[128 * 32];
  __shared__ unsigned short Bs[64 * 32];
  const int tid  = threadIdx.x;
  const int wave = tid >> 6, lane = tid & 63;
  const int q4 = lane >> 4, ln = lane & 15;
  const size_t bm = (size_t)blockIdx.x * 128;
  const size_t bn = (size_t)blockIdx.y * 64;
  const int wm = (wave >> 1) * 64, wn = (wave & 1) * 32;
  f32x4 acc[4][2] = {};
  const int srow = wave * 16 + (lane >> 2);
  const int scol = (lane & 3) * 8;

  const unsigned short* Ag  = A  + (bm + srow)      * 512 + scol;
  const unsigned short* Ag2 = A  + (bm + 64 + srow) * 512 + scol;
  const unsigned short* Bg  = Bt + (bn + srow)      * 512 + scol;
  unsigned short* Ad  = As + wave * 512;
  unsigned short* Ad2 = As + 2048 + wave * 512;
  unsigned short* Bd  = Bs + wave * 512;

  for (int kt = 0; kt < 512; kt += 32) {
    __syncthreads();
    gll16(Ag + kt,  Ad);
    gll16(Ag2 + kt, Ad2);
    gll16(Bg + kt,  Bd);
    __syncthreads();
    s16x8 af[4], bfr[2];
#pragma unroll
    for (int i = 0; i < 4; i++)
      af[i] = *(const s16x8*)(As + (wm + i * 16 + ln) * 32 + q4 * 8);
#pragma unroll
    for (int i = 0; i < 2; i++)
      bfr[i] = *(const s16x8*)(Bs + (wn + i * 16 + ln) * 32 + q4 * 8);
#pragma unroll
    for (int mi = 0; mi < 4; mi++)
#pragma unroll
      for (int ni = 0; ni < 2; ni++)
        acc[mi][ni] = __builtin_amdgcn_mfma_f32_16x16x32_bf16(
            af[mi], bfr[ni], acc[mi][ni], 0, 0, 0);
  }
#pragma unroll
  for (int mi = 0; mi < 4; mi++)
#pragma unroll
    for (int r = 0; r < 4; ++r) {
      size_t row = bm + wm + mi * 16 + q4 * 4 + r;
#pragma unroll
      for (int ni = 0; ni < 2; ni++)
        C[row * 512 + bn + wn + ni * 16 + ln] = acc[mi][ni][r];
    }
}

extern "C" void kernel_launch(void* const* d_in, const int* in_sizes, int n_in,
                              void* d_out, int out_size, void* d_ws, size_t ws_size,
                              hipStream_t stream) {
  const float* x  = (const float*)d_in[0];
  const float* Wq = (const float*)d_in[1];
  const float* Wk = (const float*)d_in[2];
  const float* Wv = (const float*)d_in[3];
  const float* Wo = (const float*)d_in[4];

  char* ws = (char*)d_ws;
  unsigned short* xb    = (unsigned short*)(ws);              //  8,388,608
  unsigned short* Wall  = (unsigned short*)(ws + 8388608);    //  2,097,152
  unsigned short* QKb   = (unsigned short*)(ws + 10485760);   // 16,777,216
  unsigned short* Vtb   = (unsigned short*)(ws + 27262976);   //  8,388,608
  unsigned short* Oc    = (unsigned short*)(ws + 35651584);   //  8,388,608
  float*          Opart = (float*)(ws + 44040192);            // 33,554,432
  float*          Lpart = (float*)(ws + 77594624);            //    524,288

  const float C2 = 0.125f * 1.44269504088896f;  // 1/sqrt(64) * log2(e)

  hipLaunchKernelGGL(prep_kernel, dim3(1280), dim3(256), 0, stream,
                     x, Wq, Wk, Wv, Wo, xb, Wall, C2);
  hipLaunchKernelGGL(gemm_qkv, dim3(64, 12), dim3(256), 0, stream,
                     xb, Wall, QKb, Vtb);
  hipLaunchKernelGGL(attn_kernel, dim3(32, 8, 4), dim3(256), 0, stream,
                     QKb, Vtb, Opart, Lpart);
  hipLaunchKernelGGL(combine_kernel, dim3(4096), dim3(256), 0, stream,
                     Opart, Lpart, Oc);
  hipLaunchKernelGGL(gemm_out, dim3(64, 8), dim3(256), 0, stream,
                     Oc, Wall + 3 * 262144, (float*)d_out);
}